// Round 4
// baseline (140.477 us; speedup 1.0000x reference)
//
#include <hip/hip_runtime.h>

// Proximity: mean over B of clipped L2 distance between L2-normalized x row
// and its label's L2-normalized center row.
// dist[i] = sxx/nx^2 + scc/nc^2 - 2*sxc/(nx*nc),  n* = max(sqrt(s**), eps)
//
// Single fused kernel: one wave per sample, per-block LDS combine,
// one atomicAdd per block into d_out[0] (zeroed by a memset node).
// NT loads on x regressed R2 (+6.7us) — keep plain cached loads.

#define EPS_MIN 1e-12f
#define CLAMP_MAX 1e12f

typedef float v4f __attribute__((ext_vector_type(4)));

__global__ __launch_bounds__(256) void prox_kernel(
    const float* __restrict__ x,
    const int* __restrict__ labels,
    const float* __restrict__ centers,
    float* __restrict__ out,
    int Bn, int Dn, float inv_B)
{
    const int wave = threadIdx.x >> 6;
    const int lane = threadIdx.x & 63;
    const int sample = blockIdx.x * 4 + wave;

    __shared__ float wsum[4];

    float d = 0.0f;
    if (sample < Bn) {
        const v4f* __restrict__ xr = (const v4f*)(x + (size_t)sample * Dn);
        const v4f* __restrict__ cr =
            (const v4f*)(centers + (size_t)labels[sample] * Dn);

        const int nf4 = Dn >> 2;            // 256 float4s per row (D=1024)
        float sxx = 0.f, scc = 0.f, sxc = 0.f;
        #pragma unroll 4
        for (int i = lane; i < nf4; i += 64) {
            v4f xv = xr[i];
            v4f cv = cr[i];
            sxx += xv.x * xv.x + xv.y * xv.y + xv.z * xv.z + xv.w * xv.w;
            scc += cv.x * cv.x + cv.y * cv.y + cv.z * cv.z + cv.w * cv.w;
            sxc += xv.x * cv.x + xv.y * cv.y + xv.z * cv.z + xv.w * cv.w;
        }
        #pragma unroll
        for (int off = 32; off > 0; off >>= 1) {
            sxx += __shfl_down(sxx, off, 64);
            scc += __shfl_down(scc, off, 64);
            sxc += __shfl_down(sxc, off, 64);
        }
        if (lane == 0) {
            float nx = fmaxf(sqrtf(sxx), EPS_MIN);
            float nc = fmaxf(sqrtf(scc), EPS_MIN);
            float v = sxx / (nx * nx) + scc / (nc * nc)
                    - 2.0f * (sxc / (nx * nc));
            d = fminf(fmaxf(v, EPS_MIN), CLAMP_MAX);
        }
    }
    if (lane == 0) wsum[wave] = d;
    __syncthreads();
    if (threadIdx.x == 0) {
        float blk = (wsum[0] + wsum[1] + wsum[2] + wsum[3]) * inv_B;
        atomicAdd(out, blk);                // device-scope, one per block
    }
}

extern "C" void kernel_launch(void* const* d_in, const int* in_sizes, int n_in,
                              void* d_out, int out_size, void* d_ws, size_t ws_size,
                              hipStream_t stream)
{
    const float* x       = (const float*)d_in[0];
    const int*   labels  = (const int*)d_in[1];
    const float* centers = (const float*)d_in[2];
    float* out = (float*)d_out;

    const int Bn = in_sizes[1];            // 16384
    const int Dn = in_sizes[0] / Bn;       // 1024

    // d_out is poisoned 0xAA before every call — zero it, then accumulate.
    hipMemsetAsync(out, 0, sizeof(float), stream);

    const int blocks = (Bn + 3) / 4;       // 4096 blocks, 1 sample per wave
    prox_kernel<<<blocks, 256, 0, stream>>>(x, labels, centers, out,
                                            Bn, Dn, 1.0f / (float)Bn);
}

// Round 5
// 104.270 us; speedup vs baseline: 1.3472x; 1.3472x over previous
//
#include <hip/hip_runtime.h>

// Proximity: mean over B of clipped L2 distance between L2-normalized x row
// and its label's L2-normalized center row.
// dist[i] = sxx/nx^2 + scc/nc^2 - 2*sxc/(nx*nc),  n* = max(sqrt(s**), eps)
//
// R4 lesson: one-shot wave-per-sample is LATENCY-bound (932 GB/s, VALUBusy 9%)
// — the wave issues 8 loads then stalls through FMA+shuffle with no memory
// traffic. R5: persistent waves, 4 samples/wave, double-buffered register
// pipeline so next sample's loads are in flight during current reduction.
// No atomics (same-address atomicAdd tail cost ~25us in R4). No NT loads (R2).

#define EPS_MIN 1e-12f
#define CLAMP_MAX 1e12f

typedef float v4f __attribute__((ext_vector_type(4)));

// Fast path: Dn == 1024 (4 float4 per lane per row). 4 waves/block,
// 4 samples/wave, 4 blocks/CU resident.
__global__ __launch_bounds__(256, 4) void prox_partial_pipe(
    const float* __restrict__ x,
    const int* __restrict__ labels,
    const float* __restrict__ centers,
    float* __restrict__ partial,
    int Bn)
{
    const int lane    = threadIdx.x & 63;
    const int wave_id = blockIdx.x * 4 + (threadIdx.x >> 6);
    const int nwaves  = gridDim.x * 4;

    v4f X[2][4], C[2][4];

    auto issue = [&](int buf, int s) {
        const v4f* __restrict__ xr = (const v4f*)(x + (size_t)s * 1024);
        const v4f* __restrict__ cr =
            (const v4f*)(centers + (size_t)labels[s] * 1024);
        #pragma unroll
        for (int j = 0; j < 4; ++j) {
            X[buf][j] = xr[lane + 64 * j];
            C[buf][j] = cr[lane + 64 * j];
        }
    };

    if (wave_id < Bn) issue(0, wave_id);

    #pragma unroll
    for (int k = 0; k < 4; ++k) {
        const int s = wave_id + k * nwaves;
        if (s < Bn) {
            const int sn = s + nwaves;
            if (k + 1 < 4 && sn < Bn) issue((k + 1) & 1, sn);  // prefetch

            const int b = k & 1;
            float sxx = 0.f, scc = 0.f, sxc = 0.f;
            #pragma unroll
            for (int j = 0; j < 4; ++j) {
                v4f xv = X[b][j], cv = C[b][j];
                sxx += xv.x * xv.x + xv.y * xv.y + xv.z * xv.z + xv.w * xv.w;
                scc += cv.x * cv.x + cv.y * cv.y + cv.z * cv.z + cv.w * cv.w;
                sxc += xv.x * cv.x + xv.y * cv.y + xv.z * cv.z + xv.w * cv.w;
            }
            #pragma unroll
            for (int off = 32; off > 0; off >>= 1) {
                sxx += __shfl_down(sxx, off, 64);
                scc += __shfl_down(scc, off, 64);
                sxc += __shfl_down(sxc, off, 64);
            }
            if (lane == 0) {
                float nx = fmaxf(sqrtf(sxx), EPS_MIN);
                float nc = fmaxf(sqrtf(scc), EPS_MIN);
                float d = sxx / (nx * nx) + scc / (nc * nc)
                        - 2.0f * (sxc / (nx * nc));
                partial[s] = fminf(fmaxf(d, EPS_MIN), CLAMP_MAX);
            }
        }
    }
}

// Generic fallback (any Dn multiple of 4), R3 structure.
__global__ __launch_bounds__(256) void prox_partial_generic(
    const float* __restrict__ x,
    const int* __restrict__ labels,
    const float* __restrict__ centers,
    float* __restrict__ partial,
    int Bn, int Dn)
{
    const int lane = threadIdx.x & 63;
    const int sample = blockIdx.x * 4 + (threadIdx.x >> 6);
    if (sample >= Bn) return;
    const v4f* __restrict__ xr = (const v4f*)(x + (size_t)sample * Dn);
    const v4f* __restrict__ cr = (const v4f*)(centers + (size_t)labels[sample] * Dn);
    const int nf4 = Dn >> 2;
    float sxx = 0.f, scc = 0.f, sxc = 0.f;
    for (int i = lane; i < nf4; i += 64) {
        v4f xv = xr[i], cv = cr[i];
        sxx += xv.x * xv.x + xv.y * xv.y + xv.z * xv.z + xv.w * xv.w;
        scc += cv.x * cv.x + cv.y * cv.y + cv.z * cv.z + cv.w * cv.w;
        sxc += xv.x * cv.x + xv.y * cv.y + xv.z * cv.z + xv.w * cv.w;
    }
    #pragma unroll
    for (int off = 32; off > 0; off >>= 1) {
        sxx += __shfl_down(sxx, off, 64);
        scc += __shfl_down(scc, off, 64);
        sxc += __shfl_down(sxc, off, 64);
    }
    if (lane == 0) {
        float nx = fmaxf(sqrtf(sxx), EPS_MIN);
        float nc = fmaxf(sqrtf(scc), EPS_MIN);
        float d = sxx / (nx * nx) + scc / (nc * nc) - 2.0f * (sxc / (nx * nc));
        partial[sample] = fminf(fmaxf(d, EPS_MIN), CLAMP_MAX);
    }
}

// Single-block deterministic reduction of Bn partials -> mean.
__global__ __launch_bounds__(1024) void prox_final_kernel(
    const float* __restrict__ partial, float* __restrict__ out,
    int n, float inv_B)
{
    float s = 0.f;
    for (int i = threadIdx.x; i < n; i += 1024) s += partial[i];
    __shared__ float smem[16];
    #pragma unroll
    for (int off = 32; off > 0; off >>= 1) s += __shfl_down(s, off, 64);
    if ((threadIdx.x & 63) == 0) smem[threadIdx.x >> 6] = s;
    __syncthreads();
    if (threadIdx.x == 0) {
        float t = 0.f;
        #pragma unroll
        for (int w = 0; w < 16; ++w) t += smem[w];
        out[0] = t * inv_B;
    }
}

extern "C" void kernel_launch(void* const* d_in, const int* in_sizes, int n_in,
                              void* d_out, int out_size, void* d_ws, size_t ws_size,
                              hipStream_t stream)
{
    const float* x       = (const float*)d_in[0];
    const int*   labels  = (const int*)d_in[1];
    const float* centers = (const float*)d_in[2];
    float* out = (float*)d_out;

    const int Bn = in_sizes[1];            // 16384
    const int Dn = in_sizes[0] / Bn;       // 1024

    float* partial = (float*)d_ws;         // Bn * 4 bytes <= ws_size

    if (Dn == 1024) {
        // 4 samples/wave, 4 waves/block -> Bn/16 blocks (1024 for B=16384)
        const int blocks = (Bn + 15) / 16;
        prox_partial_pipe<<<blocks, 256, 0, stream>>>(x, labels, centers,
                                                      partial, Bn);
    } else {
        const int blocks = (Bn + 3) / 4;
        prox_partial_generic<<<blocks, 256, 0, stream>>>(x, labels, centers,
                                                         partial, Bn, Dn);
    }
    prox_final_kernel<<<1, 1024, 0, stream>>>(partial, out, Bn,
                                              1.0f / (float)Bn);
}

// Round 6
// 104.253 us; speedup vs baseline: 1.3475x; 1.0002x over previous
//
#include <hip/hip_runtime.h>

// Proximity: mean over B of clipped L2 distance between L2-normalized x row
// and its label's L2-normalized center row.
// dist[i] = sxx/nx^2 + scc/nc^2 - 2*sxc/(nx*nc),  n* = max(sqrt(s**), eps)
//
// R4 diagnosis: stream ran at 932 GB/s because in-flight bytes/CU ~1.9KB vs
// ~9.3KB needed to hide ~900cyc HBM latency (15 waves x 8 loads x 16B).
// R6: 4 samples per wave one-shot — 32 loads (512B) in flight per wave,
// 12 waves/CU (launch_bounds 256,3) -> ~6KB/CU in flight. X loads issue
// before the label->center dependency chain. No atomics (R4), no NT (R2).

#define EPS_MIN 1e-12f
#define CLAMP_MAX 1e12f

typedef float v4f __attribute__((ext_vector_type(4)));

// Fast path: Dn == 1024. 4 waves/block, 4 consecutive samples per wave.
__global__ __launch_bounds__(256, 3) void prox_partial4(
    const float* __restrict__ x,
    const int* __restrict__ labels,
    const float* __restrict__ centers,
    float* __restrict__ partial,
    int Bn)
{
    const int lane = threadIdx.x & 63;
    const int wave = blockIdx.x * 4 + (threadIdx.x >> 6);
    const int base = wave * 4;
    if (base >= Bn) return;

    // Labels first (wave-uniform -> scalar loads), then all 16 x-loads
    // (independent, issue immediately), then all 16 center-loads.
    int lbl[4];
    #pragma unroll
    for (int i = 0; i < 4; ++i) {
        int s = base + i;
        lbl[i] = labels[(s < Bn) ? s : (Bn - 1)];
    }

    v4f X[4][4], C[4][4];
    #pragma unroll
    for (int i = 0; i < 4; ++i) {
        int s = base + i; if (s >= Bn) s = Bn - 1;
        const v4f* __restrict__ xr = (const v4f*)(x + (size_t)s * 1024);
        #pragma unroll
        for (int j = 0; j < 4; ++j) X[i][j] = xr[lane + 64 * j];
    }
    #pragma unroll
    for (int i = 0; i < 4; ++i) {
        const v4f* __restrict__ cr = (const v4f*)(centers + (size_t)lbl[i] * 1024);
        #pragma unroll
        for (int j = 0; j < 4; ++j) C[i][j] = cr[lane + 64 * j];
    }

    #pragma unroll
    for (int i = 0; i < 4; ++i) {
        float sxx = 0.f, scc = 0.f, sxc = 0.f;
        #pragma unroll
        for (int j = 0; j < 4; ++j) {
            v4f xv = X[i][j], cv = C[i][j];
            sxx += xv.x * xv.x + xv.y * xv.y + xv.z * xv.z + xv.w * xv.w;
            scc += cv.x * cv.x + cv.y * cv.y + cv.z * cv.z + cv.w * cv.w;
            sxc += xv.x * cv.x + xv.y * cv.y + xv.z * cv.z + xv.w * cv.w;
        }
        #pragma unroll
        for (int off = 32; off > 0; off >>= 1) {
            sxx += __shfl_down(sxx, off, 64);
            scc += __shfl_down(scc, off, 64);
            sxc += __shfl_down(sxc, off, 64);
        }
        const int s = base + i;
        if (lane == 0 && s < Bn) {
            float nx = fmaxf(sqrtf(sxx), EPS_MIN);
            float nc = fmaxf(sqrtf(scc), EPS_MIN);
            float d = sxx / (nx * nx) + scc / (nc * nc)
                    - 2.0f * (sxc / (nx * nc));
            partial[s] = fminf(fmaxf(d, EPS_MIN), CLAMP_MAX);
        }
    }
}

// Generic fallback (any Dn multiple of 4).
__global__ __launch_bounds__(256) void prox_partial_generic(
    const float* __restrict__ x,
    const int* __restrict__ labels,
    const float* __restrict__ centers,
    float* __restrict__ partial,
    int Bn, int Dn)
{
    const int lane = threadIdx.x & 63;
    const int sample = blockIdx.x * 4 + (threadIdx.x >> 6);
    if (sample >= Bn) return;
    const v4f* __restrict__ xr = (const v4f*)(x + (size_t)sample * Dn);
    const v4f* __restrict__ cr = (const v4f*)(centers + (size_t)labels[sample] * Dn);
    const int nf4 = Dn >> 2;
    float sxx = 0.f, scc = 0.f, sxc = 0.f;
    for (int i = lane; i < nf4; i += 64) {
        v4f xv = xr[i], cv = cr[i];
        sxx += xv.x * xv.x + xv.y * xv.y + xv.z * xv.z + xv.w * xv.w;
        scc += cv.x * cv.x + cv.y * cv.y + cv.z * cv.z + cv.w * cv.w;
        sxc += xv.x * cv.x + xv.y * cv.y + xv.z * cv.z + xv.w * cv.w;
    }
    #pragma unroll
    for (int off = 32; off > 0; off >>= 1) {
        sxx += __shfl_down(sxx, off, 64);
        scc += __shfl_down(scc, off, 64);
        sxc += __shfl_down(sxc, off, 64);
    }
    if (lane == 0) {
        float nx = fmaxf(sqrtf(sxx), EPS_MIN);
        float nc = fmaxf(sqrtf(scc), EPS_MIN);
        float d = sxx / (nx * nx) + scc / (nc * nc) - 2.0f * (sxc / (nx * nc));
        partial[sample] = fminf(fmaxf(d, EPS_MIN), CLAMP_MAX);
    }
}

// Single-block deterministic reduction of Bn partials -> mean.
__global__ __launch_bounds__(1024) void prox_final_kernel(
    const float* __restrict__ partial, float* __restrict__ out,
    int n, float inv_B)
{
    float s = 0.f;
    for (int i = threadIdx.x; i < n; i += 1024) s += partial[i];
    __shared__ float smem[16];
    #pragma unroll
    for (int off = 32; off > 0; off >>= 1) s += __shfl_down(s, off, 64);
    if ((threadIdx.x & 63) == 0) smem[threadIdx.x >> 6] = s;
    __syncthreads();
    if (threadIdx.x == 0) {
        float t = 0.f;
        #pragma unroll
        for (int w = 0; w < 16; ++w) t += smem[w];
        out[0] = t * inv_B;
    }
}

extern "C" void kernel_launch(void* const* d_in, const int* in_sizes, int n_in,
                              void* d_out, int out_size, void* d_ws, size_t ws_size,
                              hipStream_t stream)
{
    const float* x       = (const float*)d_in[0];
    const int*   labels  = (const int*)d_in[1];
    const float* centers = (const float*)d_in[2];
    float* out = (float*)d_out;

    const int Bn = in_sizes[1];            // 16384
    const int Dn = in_sizes[0] / Bn;       // 1024

    float* partial = (float*)d_ws;         // Bn * 4 bytes <= ws_size

    if (Dn == 1024) {
        const int blocks = (Bn + 15) / 16; // 1024 blocks, 4 samples/wave
        prox_partial4<<<blocks, 256, 0, stream>>>(x, labels, centers,
                                                  partial, Bn);
    } else {
        const int blocks = (Bn + 3) / 4;
        prox_partial_generic<<<blocks, 256, 0, stream>>>(x, labels, centers,
                                                         partial, Bn, Dn);
    }
    prox_final_kernel<<<1, 1024, 0, stream>>>(partial, out, Bn,
                                              1.0f / (float)Bn);
}